// Round 1
// baseline (11.625 us; speedup 1.0000x reference)
//
#include <hip/hip_runtime.h>

#define N_ATOMS 262144
#define N_MOL 8192
#define MAX_Z 100
#define MODEL_DIMS 1024

// ws layout (floats): [0..MAX_Z) = ew[z] = dot(embed[z], w)
//                     [MAX_Z..MAX_Z+3) = pw[r] = dot(w_pos[r], w)

__global__ void prep_kernel(const float* __restrict__ embed,
                            const float* __restrict__ w_pos,
                            const float* __restrict__ w,
                            const float* __restrict__ b,
                            float* __restrict__ ewpw,
                            float* __restrict__ out) {
    const int blk = blockIdx.x;
    const int tid = threadIdx.x;
    __shared__ float red[256];

    if (blk < MAX_Z + 3) {
        // one length-1024 dot product per block
        const float* row = (blk < MAX_Z) ? (embed + (size_t)blk * MODEL_DIMS)
                                         : (w_pos + (size_t)(blk - MAX_Z) * MODEL_DIMS);
        float s = 0.f;
        for (int j = tid; j < MODEL_DIMS; j += 256)
            s += row[j] * w[j];
        red[tid] = s;
        __syncthreads();
        for (int off = 128; off > 0; off >>= 1) {
            if (tid < off) red[tid] += red[tid + off];
            __syncthreads();
        }
        if (tid == 0) ewpw[blk] = red[0];
    } else {
        // last block: initialize out[m] = b  (harness poisons d_out; we must
        // fully rewrite it every call)
        const float bv = b[0];
        for (int i = tid; i < N_MOL; i += 256)
            out[i] = bv;
    }
}

__global__ void atom_kernel(const int* __restrict__ z,
                            const float* __restrict__ pos,
                            const int* __restrict__ batch,
                            const float* __restrict__ ewpw,
                            float* __restrict__ out) {
    const int i = blockIdx.x * blockDim.x + threadIdx.x;
    // broadcast scalars (L1-hot after first wave)
    const float pw0 = ewpw[MAX_Z + 0];
    const float pw1 = ewpw[MAX_Z + 1];
    const float pw2 = ewpw[MAX_Z + 2];

    const int   id = batch[i];
    const int   zi = z[i];
    const float p0 = pos[3 * (size_t)i + 0];
    const float p1 = pos[3 * (size_t)i + 1];
    const float p2 = pos[3 * (size_t)i + 2];

    float v = ewpw[zi] + p0 * pw0 + p1 * pw1 + p2 * pw2;

    // batch is globally sorted -> ids within a wave are non-decreasing.
    // Segmented inclusive scan across the 64-lane wave.
    const int lane = threadIdx.x & 63;
    #pragma unroll
    for (int off = 1; off < 64; off <<= 1) {
        float vu = __shfl_up(v, off);
        int   iu = __shfl_up(id, off);
        if (lane >= off && iu == id) v += vu;
    }
    // lane is the last of its segment within the wave -> one atomic per segment
    const int idn = __shfl_down(id, 1);
    const bool seg_last = (lane == 63) || (idn != id);
    if (seg_last) atomicAdd(&out[id], v);
}

extern "C" void kernel_launch(void* const* d_in, const int* in_sizes, int n_in,
                              void* d_out, int out_size, void* d_ws, size_t ws_size,
                              hipStream_t stream) {
    const int*   atomic_numbers = (const int*)d_in[0];
    const float* pos            = (const float*)d_in[1];
    const int*   batch          = (const int*)d_in[2];
    const float* embed          = (const float*)d_in[3];
    const float* w_pos          = (const float*)d_in[4];
    const float* w              = (const float*)d_in[5];
    const float* b              = (const float*)d_in[6];
    float*       out            = (float*)d_out;
    float*       ewpw           = (float*)d_ws;

    // Kernel 1: 103 dot products + out init (block MAX_Z+3)
    prep_kernel<<<MAX_Z + 4, 256, 0, stream>>>(embed, w_pos, w, b, ewpw, out);

    // Kernel 2: per-atom scalar + segmented wave reduction + atomic scatter
    atom_kernel<<<N_ATOMS / 256, 256, 0, stream>>>(atomic_numbers, pos, batch,
                                                   ewpw, out);
}